// Round 9
// baseline (348.157 us; speedup 1.0000x reference)
//
#include <hip/hip_runtime.h>
#include <math.h>

typedef __attribute__((ext_vector_type(8))) short short8b;   // 8 bf16 = 4 VGPR
typedef __attribute__((ext_vector_type(4))) float f32x4;

#define B_   16
#define C_   256
#define N_   16384      // H*W
#define NH_  4
#define G_   8
#define CPG_ 32

// Workspace layout (float offsets) — total ~196 KB (proven-safe < 332 KB)
#define OFF_S    0        // [B][C] folded GN scale   (k_stats writes SUM here first)
#define OFF_T    4096     // [B][C] folded GN shift   (k_stats writes SQ here first)
#define OFF_SUM  OFF_S
#define OFF_SQ   OFF_T
#define OFF_M    8192     // [B][4][16][16] f32
#define OFF_Z    24576    // [B][64] f32
#define OFF_GATE 25600    // [B]
#define OFF_WKVQ 25616    // bf16 [192][256] (24576 floats)

static __device__ inline unsigned short bf16u(float f) {
    unsigned int u = __float_as_uint(f);
    return (unsigned short)((u + 0x7FFFu + ((u >> 16) & 1u)) >> 16);   // RNE
}
static __device__ inline float ubf(unsigned short u) {
    return __uint_as_float(((unsigned int)u) << 16);
}

// ---------------------------------------------------------------------------
// K1: per-(b,c) sum and sumsq over pixels. One block per (b,c).
// ---------------------------------------------------------------------------
__global__ __launch_bounds__(256) void k_stats(const float* __restrict__ x,
                                               float* __restrict__ ws) {
    const int bc = blockIdx.x;
    const float4* p4 = (const float4*)(x + (size_t)bc * N_);
    float s = 0.f, q = 0.f;
    #pragma unroll 4
    for (int i = threadIdx.x; i < N_ / 4; i += 256) {
        float4 v = p4[i];
        s += v.x + v.y + v.z + v.w;
        q += v.x * v.x + v.y * v.y + v.z * v.z + v.w * v.w;
    }
    #pragma unroll
    for (int o = 32; o > 0; o >>= 1) {
        s += __shfl_down(s, o);
        q += __shfl_down(q, o);
    }
    __shared__ float ls[4], lq[4];
    const int wid = threadIdx.x >> 6, lane = threadIdx.x & 63;
    if (lane == 0) { ls[wid] = s; lq[wid] = q; }
    __syncthreads();
    if (threadIdx.x == 0) {
        ws[OFF_SUM + bc] = ls[0] + ls[1] + ls[2] + ls[3];
        ws[OFF_SQ  + bc] = lq[0] + lq[1] + lq[2] + lq[3];
    }
}

// ---------------------------------------------------------------------------
// K_cvtw: Wk|Wv|Wq -> bf16 table [192][256], row-major (K contiguous).
// ---------------------------------------------------------------------------
__global__ __launch_bounds__(256) void k_cvtw(const float* __restrict__ Wk,
        const float* __restrict__ Wv, const float* __restrict__ Wq,
        float* __restrict__ ws) {
    unsigned short* wkvq = (unsigned short*)(ws + OFF_WKVQ);
    const int r = blockIdx.x, t = threadIdx.x;
    const float* src = r < 64 ? Wk + r * C_
                     : r < 128 ? Wv + (r - 64) * C_
                     : Wq + (r - 128) * C_;
    wkvq[r * 256 + t] = bf16u(src[t]);
}

// ---------------------------------------------------------------------------
// K2: per-batch prep — GN fold (in-place over SUM/SQ), gate MLP, M/Z init.
// ---------------------------------------------------------------------------
__global__ __launch_bounds__(256) void k_prep(
        const float* __restrict__ gnw, const float* __restrict__ gnb,
        const float* __restrict__ M0,  const float* __restrict__ Z0,
        const float* __restrict__ g1w, const float* __restrict__ g1b,
        const float* __restrict__ g2w, const float* __restrict__ g2b,
        float* __restrict__ ws, float* __restrict__ out_gate) {
    const int b = blockIdx.x, t = threadIdx.x;
    __shared__ float mu[G_], rs[G_];
    __shared__ float pooled[C_];
    __shared__ float hidden[64];

    if (t < G_) {
        float S = 0.f, Q = 0.f;
        for (int c = t * CPG_; c < (t + 1) * CPG_; ++c) {
            S += ws[OFF_SUM + b * C_ + c];
            Q += ws[OFF_SQ  + b * C_ + c];
        }
        const float cnt = (float)(CPG_ * N_);
        const float m = S / cnt;
        const float var = Q / cnt - m * m;
        mu[t] = m;
        rs[t] = rsqrtf(var + 1e-5f);
    }
    __syncthreads();
    {
        const int c = t;
        const int g = c / CPG_;
        const float sumc = ws[OFF_SUM + b * C_ + c];   // read BEFORE in-place overwrite
        const float sc = rs[g] * gnw[c];
        const float tc = gnb[c] - mu[g] * sc;
        ws[OFF_S + b * C_ + c] = sc;
        ws[OFF_T + b * C_ + c] = tc;
        pooled[c] = fmaf(sumc * (1.f / (float)N_), sc, tc);
    }
    __syncthreads();
    if (t < 64) {
        float a = g1b[t];
        for (int c = 0; c < C_; ++c) a = fmaf(pooled[c], g1w[t * C_ + c], a);
        hidden[t] = 0.5f * a * (1.f + erff(a * 0.70710678118654752f));
    }
    __syncthreads();
    if (t == 0) {
        float z = g2b[0];
        for (int j = 0; j < 64; ++j) z = fmaf(hidden[j], g2w[j], z);
        const float gate = 1.f / (1.f + expf(-z));
        ws[OFF_GATE + b] = gate;
        out_gate[b] = gate;
    }
    for (int i = t; i < NH_ * 256; i += 256) ws[OFF_M + b * 1024 + i] = M0[i];
    for (int i = t; i < 64;        i += 256) ws[OFF_Z + b * 64 + i]   = Z0[i];
}

// ---------------------------------------------------------------------------
// K3 (MFMA, fused): K|V projection GEMM ([128 rows][128 px], K=256) then
// in-block M += phik·v^T and Z row-sums. (unchanged — proven)
// ---------------------------------------------------------------------------
__global__ __launch_bounds__(256) void k_projmz(const float* __restrict__ x,
                                                float* __restrict__ ws) {
    __shared__ __align__(16) char lds[35072];
    char* w_s = lds;                          // [128][80B]  phase A
    char* x_s = lds + 10240;                  // [128][80B]  phase A
    unsigned short (*kvt)[136] = (unsigned short (*)[136])lds;   // phase B/C, aliases A
    float* z_red = (float*)(lds + 34816);     // [64], outside the aliased region

    const int b = blockIdx.y, px0 = blockIdx.x * 128;
    const int t = threadIdx.x, w = t >> 6, l = t & 63;
    const float* __restrict__ sv = ws + OFF_S + b * C_;
    const float* __restrict__ tv = ws + OFF_T + b * C_;
    const unsigned int* __restrict__ wkvq32 = (const unsigned int*)(ws + OFF_WKVQ);
    const float* __restrict__ xb = x + (size_t)b * C_ * N_ + px0;

    if (t < 64) z_red[t] = 0.f;

    f32x4 acc[2][8];
    #pragma unroll
    for (int i = 0; i < 2; ++i)
        #pragma unroll
        for (int j = 0; j < 8; ++j) acc[i][j] = (f32x4){0.f, 0.f, 0.f, 0.f};

    for (int ks = 0; ks < 8; ++ks) {
        __syncthreads();
        #pragma unroll
        for (int i = 0; i < 8; ++i) {
            const int e2 = t + 256 * i;
            const int row = e2 >> 4, kp = e2 & 15;
            *(unsigned int*)(w_s + row * 80 + kp * 4) =
                wkvq32[row * 128 + ks * 16 + kp];
        }
        {
            const int px = t & 127, half = t >> 7;
            #pragma unroll
            for (int i = 0; i < 8; ++i) {
                const int lc = half * 16 + i * 2;
                const int c = ks * 32 + lc;
                const float a0 = fmaf(xb[(size_t)c * N_ + px],       sv[c],     tv[c]);
                const float a1 = fmaf(xb[(size_t)(c + 1) * N_ + px], sv[c + 1], tv[c + 1]);
                *(unsigned int*)(x_s + px * 80 + lc * 2) =
                    ((unsigned int)bf16u(a1) << 16) | bf16u(a0);
            }
        }
        __syncthreads();
        short8b bfr[8];
        #pragma unroll
        for (int ct = 0; ct < 8; ++ct)
            bfr[ct] = *(const short8b*)(x_s + (ct * 16 + (l & 15)) * 80 + (l >> 4) * 16);
        #pragma unroll
        for (int rt = 0; rt < 2; ++rt) {
            const int row = w * 32 + rt * 16 + (l & 15);
            const short8b af = *(const short8b*)(w_s + row * 80 + (l >> 4) * 16);
            #pragma unroll
            for (int ct = 0; ct < 8; ++ct)
                acc[rt][ct] = __builtin_amdgcn_mfma_f32_16x16x32_bf16(
                                  af, bfr[ct], acc[rt][ct], 0, 0, 0);
        }
    }
    __syncthreads();   // staging buffers dead; safe to overwrite with kvt

    #pragma unroll
    for (int rt = 0; rt < 2; ++rt) {
        const int base = w * 32 + rt * 16;
        const bool do_elu = base < 64;
        #pragma unroll
        for (int ct = 0; ct < 8; ++ct) {
            const int px = ct * 16 + (l & 15);
            #pragma unroll
            for (int r = 0; r < 4; ++r) {
                const int row = base + (l >> 4) * 4 + r;
                float v = acc[rt][ct][r];
                if (do_elu) v = v > 0.f ? v + 1.f : __expf(v);
                kvt[row][px] = bf16u(v);
            }
        }
    }
    __syncthreads();

    f32x4 accm = (f32x4){0.f, 0.f, 0.f, 0.f};
    #pragma unroll
    for (int kc = 0; kc < 4; ++kc) {
        const short8b af = *(const short8b*)((const char*)&kvt[w * 16 + (l & 15)][0]
                                             + kc * 64 + (l >> 4) * 16);
        const short8b bf = *(const short8b*)((const char*)&kvt[64 + w * 16 + (l & 15)][0]
                                             + kc * 64 + (l >> 4) * 16);
        accm = __builtin_amdgcn_mfma_f32_16x16x32_bf16(af, bf, accm, 0, 0, 0);
    }
    {
        const int zrow = t >> 2, zq = t & 3;
        float z = 0.f;
        #pragma unroll
        for (int j = 0; j < 16; ++j) {
            const unsigned int u = *(const unsigned int*)&kvt[zrow][zq * 32 + j * 2];
            z += ubf((unsigned short)u) + ubf((unsigned short)(u >> 16));
        }
        atomicAdd(&z_red[zrow], z);
    }
    #pragma unroll
    for (int r = 0; r < 4; ++r) {
        const int d = (l >> 4) * 4 + r, e = l & 15;
        atomicAdd(&ws[OFF_M + b * 1024 + w * 256 + d * 16 + e], accm[r]);
    }
    __syncthreads();
    if (t < 64) atomicAdd(&ws[OFF_Z + b * 64 + t], z_red[t]);
}

// ---------------------------------------------------------------------------
// K4 (MFMA): 128-px tile, 512 threads, LDS 50176 B -> 3 blocks/CU (24 waves).
// Region A (16KB) is time-multiplexed: staging dbuf (2x8KB, 64B swizzled rows)
// -> m_s (4KB) -> psi (16KB), all barrier-separated. w2 32KB, bo 1KB.
// Wave w -> head w>>1, px-half-64 (w&1). Same numerics as round 8.
// ---------------------------------------------------------------------------
__global__ __launch_bounds__(512, 6) void k_out6(const float* __restrict__ x,
        const float* __restrict__ Wo, const float* __restrict__ bo,
        const float* __restrict__ ws, float* __restrict__ out) {
    __shared__ __align__(16) char lds[50176];
    char*  regA = lds;                      // staging dbuf / m_s / psi (16KB)
    char*  w2_s = lds + 16384;              // [256][128B] XOR-swizzled (32KB)
    float* bo_s = (float*)(lds + 49152);    // [256]

    const int b = blockIdx.y, px0 = blockIdx.x * 128;
    const int t = threadIdx.x, w = t >> 6, l = t & 63;
    const int h = w >> 1;                   // head
    const int pxw = (w & 1) * 64;           // px quarter-pair owned in MFMA phases
    const float* __restrict__ sv = ws + OFF_S + b * C_;
    const float* __restrict__ tv = ws + OFF_T + b * C_;
    const unsigned short* __restrict__ wkvq16 = (const unsigned short*)(ws + OFF_WKVQ);
    const float* __restrict__ xb = x + (size_t)b * C_ * N_ + px0;

    if (t < 256) bo_s[t] = bo[t];
    float zr[4];
    #pragma unroll
    for (int r = 0; r < 4; ++r)
        zr[r] = ws[OFF_Z + b * 64 + h * 16 + (l >> 4) * 4 + r];

    // Wq fragments for all 8 K-steps -> registers (row = 128 + h*16 + (l&15))
    short8b afq[8];
    {
        const unsigned short* wq = wkvq16
            + (size_t)(128 + h * 16 + (l & 15)) * 256 + (l >> 4) * 8;
        #pragma unroll
        for (int ks = 0; ks < 8; ++ks) afq[ks] = *(const short8b*)(wq + ks * 32);
    }

    const int px_ = t & 127, q = t >> 7;    // q = 0..3, 8 channels each
    char* xs0 = regA;
    char* xs1 = regA + 8192;
    const int swzA = ((px_ >> 1) & 3) << 4; // 16B-granular staging swizzle

    f32x4 accq[4];
    #pragma unroll
    for (int j = 0; j < 4; ++j) accq[j] = (f32x4){0.f, 0.f, 0.f, 0.f};

    // ---- phase 1: phi_q GEMM, double-buffered with early reg prefetch ----
    {   // prologue: stage ks=0 into xs0
        float xf[8];
        #pragma unroll
        for (int i = 0; i < 8; ++i)
            xf[i] = xb[(size_t)(q * 8 + i) * N_ + px_];
        #pragma unroll
        for (int j = 0; j < 4; ++j) {
            const int c = q * 8 + 2 * j;
            const float a0 = fmaf(xf[2 * j],     sv[c],     tv[c]);
            const float a1 = fmaf(xf[2 * j + 1], sv[c + 1], tv[c + 1]);
            *(unsigned int*)(xs0 + px_ * 64 + ((q * 16 + 4 * j) ^ swzA)) =
                ((unsigned int)bf16u(a1) << 16) | bf16u(a0);
        }
    }
    __syncthreads();
    #pragma unroll
    for (int ks = 0; ks < 8; ++ks) {
        char* xcur = (ks & 1) ? xs1 : xs0;
        char* xnxt = (ks & 1) ? xs0 : xs1;
        float xg[8];
        if (ks < 7) {                        // issue next-tile loads EARLY
            #pragma unroll
            for (int i = 0; i < 8; ++i)
                xg[i] = xb[(size_t)((ks + 1) * 32 + q * 8 + i) * N_ + px_];
        }
        #pragma unroll
        for (int ct = 0; ct < 4; ++ct) {     // MFMA on current buffer
            const int px = pxw + ct * 16 + (l & 15);
            const short8b bfr = *(const short8b*)(xcur + px * 64
                                  + (((l >> 4) * 16) ^ (((px >> 1) & 3) << 4)));
            accq[ct] = __builtin_amdgcn_mfma_f32_16x16x32_bf16(
                           afq[ks], bfr, accq[ct], 0, 0, 0);
        }
        if (ks < 7) {                        // fold + write next buffer LATE
            #pragma unroll
            for (int j = 0; j < 4; ++j) {
                const int c = (ks + 1) * 32 + q * 8 + 2 * j;
                const float a0 = fmaf(xg[2 * j],     sv[c],     tv[c]);
                const float a1 = fmaf(xg[2 * j + 1], sv[c + 1], tv[c + 1]);
                *(unsigned int*)(xnxt + px_ * 64 + ((q * 16 + 4 * j) ^ swzA)) =
                    ((unsigned int)bf16u(a1) << 16) | bf16u(a0);
            }
        }
        __syncthreads();
    }

    // ---- m_s into region A (staging dead) ----
    float* m_s = (float*)regA;
    for (int i = t; i < 1024; i += 512) m_s[i] = ws[OFF_M + b * 1024 + i];
    __syncthreads();

    // ---- W2 = Wo·M^T -> w2_s ----
    {
        const int c = t & 255, hp = t >> 8;  // 2 heads per thread
        #pragma unroll
        for (int hh = 0; hh < 2; ++hh) {
            const int hw = hp * 2 + hh;
            float wrow[16];
            #pragma unroll
            for (int j = 0; j < 4; ++j)
                *(float4*)&wrow[j * 4] = *(const float4*)&Wo[c * 64 + hw * 16 + j * 4];
            float av[16];
            #pragma unroll
            for (int d = 0; d < 16; ++d) {
                float a = 0.f;
                #pragma unroll
                for (int e = 0; e < 16; ++e)
                    a = fmaf(wrow[e], m_s[hw * 256 + d * 16 + e], a);
                av[d] = a;
            }
            #pragma unroll
            for (int j = 0; j < 8; ++j) {
                const unsigned int pk = (unsigned int)bf16u(av[2 * j])
                                      | ((unsigned int)bf16u(av[2 * j + 1]) << 16);
                *(unsigned int*)(w2_s + c * 128 + ((hw * 32 + j * 4) ^ ((c & 7) << 4))) = pk;
            }
        }
    }
    __syncthreads();   // m_s reads done before psi overwrites region A

    // ---- phi, per-pixel den (in-wave shuffle), psi -> region A (swizzled) ----
    char* pq_s = regA;                       // [128][128B]
    #pragma unroll
    for (int ct = 0; ct < 4; ++ct) {
        float p[4];
        #pragma unroll
        for (int r = 0; r < 4; ++r) {
            const float v = accq[ct][r];
            p[r] = v > 0.f ? v + 1.f : __expf(v);
        }
        float dp = 0.f;
        #pragma unroll
        for (int r = 0; r < 4; ++r) dp = fmaf(zr[r], p[r], dp);
        dp += __shfl_xor(dp, 16);
        dp += __shfl_xor(dp, 32);
        const float rd = 1.f / fmaxf(dp, 1e-4f);
        const int px = pxw + ct * 16 + (l & 15);
        const unsigned int lo = (unsigned int)bf16u(p[0] * rd)
                              | ((unsigned int)bf16u(p[1] * rd) << 16);
        const unsigned int hi = (unsigned int)bf16u(p[2] * rd)
                              | ((unsigned int)bf16u(p[3] * rd) << 16);
        const int off = (h * 32 + (l >> 4) * 8) ^ ((px & 7) << 4);
        *(unsigned long long*)(pq_s + px * 128 + off) =
            (unsigned long long)lo | ((unsigned long long)hi << 32);
    }
    __syncthreads();   // psi + W2 visible to all waves

    // ---- phase 3: out = W2 · psi (K=64); fused epilogue ----
    const float gate = ws[OFF_GATE + b];
    const float* __restrict__ xr = x + (size_t)b * C_ * N_ + px0;
    float* __restrict__ ob = out + (size_t)b * C_ * N_ + px0;
    #pragma unroll
    for (int rt = 0; rt < 4; ++rt) {
        f32x4 acc[4];
        #pragma unroll
        for (int j = 0; j < 4; ++j) acc[j] = (f32x4){0.f, 0.f, 0.f, 0.f};
        const int row = h * 64 + rt * 16 + (l & 15);
        #pragma unroll
        for (int ksi = 0; ksi < 2; ++ksi) {
            const short8b af = *(const short8b*)(w2_s + row * 128
                                 + ((ksi * 64 + (l >> 4) * 16) ^ ((row & 7) << 4)));
            #pragma unroll
            for (int ct = 0; ct < 4; ++ct) {
                const int px = pxw + ct * 16 + (l & 15);
                const short8b bfr = *(const short8b*)(pq_s + px * 128
                                 + ((ksi * 64 + (l >> 4) * 16) ^ ((px & 7) << 4)));
                acc[ct] = __builtin_amdgcn_mfma_f32_16x16x32_bf16(
                              af, bfr, acc[ct], 0, 0, 0);
            }
        }
        #pragma unroll
        for (int ct = 0; ct < 4; ++ct) {
            const int px = pxw + ct * 16 + (l & 15);
            #pragma unroll
            for (int r = 0; r < 4; ++r) {
                const int orow = h * 64 + rt * 16 + (l >> 4) * 4 + r;
                const size_t off = (size_t)orow * N_ + px;
                ob[off] = fmaf(gate, acc[ct][r] + bo_s[orow], xr[off]);
            }
        }
    }
}

// ---------------------------------------------------------------------------
extern "C" void kernel_launch(void* const* d_in, const int* in_sizes, int n_in,
                              void* d_out, int out_size, void* d_ws, size_t ws_size,
                              hipStream_t stream) {
    const float* x   = (const float*)d_in[0];
    const float* gnw = (const float*)d_in[1];
    const float* gnb = (const float*)d_in[2];
    const float* Wk  = (const float*)d_in[3];
    const float* Wv  = (const float*)d_in[4];
    const float* Wq  = (const float*)d_in[5];
    const float* Wo  = (const float*)d_in[6];
    const float* bo  = (const float*)d_in[7];
    const float* M0  = (const float*)d_in[8];
    const float* Z0  = (const float*)d_in[9];
    const float* g1w = (const float*)d_in[10];
    const float* g1b = (const float*)d_in[11];
    const float* g2w = (const float*)d_in[12];
    const float* g2b = (const float*)d_in[13];
    float* out = (float*)d_out;
    float* ws  = (float*)d_ws;

    hipLaunchKernelGGL(k_stats,  dim3(B_ * C_), dim3(256), 0, stream, x, ws);
    hipLaunchKernelGGL(k_cvtw,   dim3(192),     dim3(256), 0, stream, Wk, Wv, Wq, ws);
    hipLaunchKernelGGL(k_prep,   dim3(B_),      dim3(256), 0, stream,
                       gnw, gnb, M0, Z0, g1w, g1b, g2w, g2b, ws,
                       out + (size_t)B_ * C_ * N_);
    hipLaunchKernelGGL(k_projmz, dim3(N_ / 128, B_), dim3(256), 0, stream, x, ws);
    hipLaunchKernelGGL(k_out6,   dim3(N_ / 128, B_), dim3(512), 0, stream,
                       x, Wo, bo, ws, out);
}

// Round 10
// 289.068 us; speedup vs baseline: 1.2044x; 1.2044x over previous
//
#include <hip/hip_runtime.h>
#include <math.h>

typedef __attribute__((ext_vector_type(8))) short short8b;   // 8 bf16 = 4 VGPR
typedef __attribute__((ext_vector_type(4))) float f32x4;

#define B_   16
#define C_   256
#define N_   16384      // H*W
#define NH_  4
#define G_   8
#define CPG_ 32

// Workspace layout (float offsets) — total ~196 KB (proven-safe < 332 KB)
#define OFF_S    0        // [B][C] folded GN scale   (k_stats writes SUM here first)
#define OFF_T    4096     // [B][C] folded GN shift   (k_stats writes SQ here first)
#define OFF_SUM  OFF_S
#define OFF_SQ   OFF_T
#define OFF_M    8192     // [B][4][16][16] f32
#define OFF_Z    24576    // [B][64] f32
#define OFF_GATE 25600    // [B]
#define OFF_WKVQ 25616    // bf16 [192][256] (24576 floats)

static __device__ inline unsigned short bf16u(float f) {
    unsigned int u = __float_as_uint(f);
    return (unsigned short)((u + 0x7FFFu + ((u >> 16) & 1u)) >> 16);   // RNE
}
static __device__ inline float ubf(unsigned short u) {
    return __uint_as_float(((unsigned int)u) << 16);
}

// ---------------------------------------------------------------------------
// K1: per-(b,c) sum and sumsq over pixels. One block per (b,c).
// ---------------------------------------------------------------------------
__global__ __launch_bounds__(256) void k_stats(const float* __restrict__ x,
                                               float* __restrict__ ws) {
    const int bc = blockIdx.x;
    const float4* p4 = (const float4*)(x + (size_t)bc * N_);
    float s = 0.f, q = 0.f;
    #pragma unroll 4
    for (int i = threadIdx.x; i < N_ / 4; i += 256) {
        float4 v = p4[i];
        s += v.x + v.y + v.z + v.w;
        q += v.x * v.x + v.y * v.y + v.z * v.z + v.w * v.w;
    }
    #pragma unroll
    for (int o = 32; o > 0; o >>= 1) {
        s += __shfl_down(s, o);
        q += __shfl_down(q, o);
    }
    __shared__ float ls[4], lq[4];
    const int wid = threadIdx.x >> 6, lane = threadIdx.x & 63;
    if (lane == 0) { ls[wid] = s; lq[wid] = q; }
    __syncthreads();
    if (threadIdx.x == 0) {
        ws[OFF_SUM + bc] = ls[0] + ls[1] + ls[2] + ls[3];
        ws[OFF_SQ  + bc] = lq[0] + lq[1] + lq[2] + lq[3];
    }
}

// ---------------------------------------------------------------------------
// K_cvtw: Wk|Wv|Wq -> bf16 table [192][256], row-major (K contiguous).
// ---------------------------------------------------------------------------
__global__ __launch_bounds__(256) void k_cvtw(const float* __restrict__ Wk,
        const float* __restrict__ Wv, const float* __restrict__ Wq,
        float* __restrict__ ws) {
    unsigned short* wkvq = (unsigned short*)(ws + OFF_WKVQ);
    const int r = blockIdx.x, t = threadIdx.x;
    const float* src = r < 64 ? Wk + r * C_
                     : r < 128 ? Wv + (r - 64) * C_
                     : Wq + (r - 128) * C_;
    wkvq[r * 256 + t] = bf16u(src[t]);
}

// ---------------------------------------------------------------------------
// K2: per-batch prep — GN fold (in-place over SUM/SQ), gate MLP, M/Z init.
// ---------------------------------------------------------------------------
__global__ __launch_bounds__(256) void k_prep(
        const float* __restrict__ gnw, const float* __restrict__ gnb,
        const float* __restrict__ M0,  const float* __restrict__ Z0,
        const float* __restrict__ g1w, const float* __restrict__ g1b,
        const float* __restrict__ g2w, const float* __restrict__ g2b,
        float* __restrict__ ws, float* __restrict__ out_gate) {
    const int b = blockIdx.x, t = threadIdx.x;
    __shared__ float mu[G_], rs[G_];
    __shared__ float pooled[C_];
    __shared__ float hidden[64];

    if (t < G_) {
        float S = 0.f, Q = 0.f;
        for (int c = t * CPG_; c < (t + 1) * CPG_; ++c) {
            S += ws[OFF_SUM + b * C_ + c];
            Q += ws[OFF_SQ  + b * C_ + c];
        }
        const float cnt = (float)(CPG_ * N_);
        const float m = S / cnt;
        const float var = Q / cnt - m * m;
        mu[t] = m;
        rs[t] = rsqrtf(var + 1e-5f);
    }
    __syncthreads();
    {
        const int c = t;
        const int g = c / CPG_;
        const float sumc = ws[OFF_SUM + b * C_ + c];   // read BEFORE in-place overwrite
        const float sc = rs[g] * gnw[c];
        const float tc = gnb[c] - mu[g] * sc;
        ws[OFF_S + b * C_ + c] = sc;
        ws[OFF_T + b * C_ + c] = tc;
        pooled[c] = fmaf(sumc * (1.f / (float)N_), sc, tc);
    }
    __syncthreads();
    if (t < 64) {
        float a = g1b[t];
        for (int c = 0; c < C_; ++c) a = fmaf(pooled[c], g1w[t * C_ + c], a);
        hidden[t] = 0.5f * a * (1.f + erff(a * 0.70710678118654752f));
    }
    __syncthreads();
    if (t == 0) {
        float z = g2b[0];
        for (int j = 0; j < 64; ++j) z = fmaf(hidden[j], g2w[j], z);
        const float gate = 1.f / (1.f + expf(-z));
        ws[OFF_GATE + b] = gate;
        out_gate[b] = gate;
    }
    for (int i = t; i < NH_ * 256; i += 256) ws[OFF_M + b * 1024 + i] = M0[i];
    for (int i = t; i < 64;        i += 256) ws[OFF_Z + b * 64 + i]   = Z0[i];
}

// ---------------------------------------------------------------------------
// K3 (MFMA, fused): K|V projection GEMM ([128 rows][128 px], K=256) then
// in-block M += phik·v^T and Z row-sums. K-loop start staggered per block so
// concurrent blocks read different channel slices (DRAM channel spreading).
// ---------------------------------------------------------------------------
__global__ __launch_bounds__(256) void k_projmz(const float* __restrict__ x,
                                                float* __restrict__ ws) {
    __shared__ __align__(16) char lds[35072];
    char* w_s = lds;                          // [128][80B]  phase A
    char* x_s = lds + 10240;                  // [128][80B]  phase A
    unsigned short (*kvt)[136] = (unsigned short (*)[136])lds;   // phase B/C, aliases A
    float* z_red = (float*)(lds + 34816);     // [64], outside the aliased region

    const int b = blockIdx.y, px0 = blockIdx.x * 128;
    const int t = threadIdx.x, w = t >> 6, l = t & 63;
    const int stag = blockIdx.x & 7;          // K-loop start stagger
    const float* __restrict__ sv = ws + OFF_S + b * C_;
    const float* __restrict__ tv = ws + OFF_T + b * C_;
    const unsigned int* __restrict__ wkvq32 = (const unsigned int*)(ws + OFF_WKVQ);
    const float* __restrict__ xb = x + (size_t)b * C_ * N_ + px0;

    if (t < 64) z_red[t] = 0.f;

    f32x4 acc[2][8];
    #pragma unroll
    for (int i = 0; i < 2; ++i)
        #pragma unroll
        for (int j = 0; j < 8; ++j) acc[i][j] = (f32x4){0.f, 0.f, 0.f, 0.f};

    for (int kk = 0; kk < 8; ++kk) {
        const int ks = (stag + kk) & 7;
        __syncthreads();
        #pragma unroll
        for (int i = 0; i < 8; ++i) {
            const int e2 = t + 256 * i;
            const int row = e2 >> 4, kp = e2 & 15;
            *(unsigned int*)(w_s + row * 80 + kp * 4) =
                wkvq32[row * 128 + ks * 16 + kp];
        }
        {
            const int px = t & 127, half = t >> 7;
            #pragma unroll
            for (int i = 0; i < 8; ++i) {
                const int lc = half * 16 + i * 2;
                const int c = ks * 32 + lc;
                const float a0 = fmaf(xb[(size_t)c * N_ + px],       sv[c],     tv[c]);
                const float a1 = fmaf(xb[(size_t)(c + 1) * N_ + px], sv[c + 1], tv[c + 1]);
                *(unsigned int*)(x_s + px * 80 + lc * 2) =
                    ((unsigned int)bf16u(a1) << 16) | bf16u(a0);
            }
        }
        __syncthreads();
        short8b bfr[8];
        #pragma unroll
        for (int ct = 0; ct < 8; ++ct)
            bfr[ct] = *(const short8b*)(x_s + (ct * 16 + (l & 15)) * 80 + (l >> 4) * 16);
        #pragma unroll
        for (int rt = 0; rt < 2; ++rt) {
            const int row = w * 32 + rt * 16 + (l & 15);
            const short8b af = *(const short8b*)(w_s + row * 80 + (l >> 4) * 16);
            #pragma unroll
            for (int ct = 0; ct < 8; ++ct)
                acc[rt][ct] = __builtin_amdgcn_mfma_f32_16x16x32_bf16(
                                  af, bfr[ct], acc[rt][ct], 0, 0, 0);
        }
    }
    __syncthreads();   // staging buffers dead; safe to overwrite with kvt

    #pragma unroll
    for (int rt = 0; rt < 2; ++rt) {
        const int base = w * 32 + rt * 16;
        const bool do_elu = base < 64;
        #pragma unroll
        for (int ct = 0; ct < 8; ++ct) {
            const int px = ct * 16 + (l & 15);
            #pragma unroll
            for (int r = 0; r < 4; ++r) {
                const int row = base + (l >> 4) * 4 + r;
                float v = acc[rt][ct][r];
                if (do_elu) v = v > 0.f ? v + 1.f : __expf(v);
                kvt[row][px] = bf16u(v);
            }
        }
    }
    __syncthreads();

    f32x4 accm = (f32x4){0.f, 0.f, 0.f, 0.f};
    #pragma unroll
    for (int kc = 0; kc < 4; ++kc) {
        const short8b af = *(const short8b*)((const char*)&kvt[w * 16 + (l & 15)][0]
                                             + kc * 64 + (l >> 4) * 16);
        const short8b bf = *(const short8b*)((const char*)&kvt[64 + w * 16 + (l & 15)][0]
                                             + kc * 64 + (l >> 4) * 16);
        accm = __builtin_amdgcn_mfma_f32_16x16x32_bf16(af, bf, accm, 0, 0, 0);
    }
    {
        const int zrow = t >> 2, zq = t & 3;
        float z = 0.f;
        #pragma unroll
        for (int j = 0; j < 16; ++j) {
            const unsigned int u = *(const unsigned int*)&kvt[zrow][zq * 32 + j * 2];
            z += ubf((unsigned short)u) + ubf((unsigned short)(u >> 16));
        }
        atomicAdd(&z_red[zrow], z);
    }
    #pragma unroll
    for (int r = 0; r < 4; ++r) {
        const int d = (l >> 4) * 4 + r, e = l & 15;
        atomicAdd(&ws[OFF_M + b * 1024 + w * 256 + d * 16 + e], accm[r]);
    }
    __syncthreads();
    if (t < 64) atomicAdd(&ws[OFF_Z + b * 64 + t], z_red[t]);
}

// ---------------------------------------------------------------------------
// K4 (MFMA): round-8 k_out5 structure (256-px tile, 512 threads, 74.7KB LDS,
// 2 blocks/CU) + per-block K-loop stagger on the x-reads and rt stagger on
// the out-writes (DRAM channel spreading). Numerics identical up to fp
// accumulation order.
// ---------------------------------------------------------------------------
__global__ __launch_bounds__(512, 4) void k_out5(const float* __restrict__ x,
        const float* __restrict__ Wo, const float* __restrict__ bo,
        const float* __restrict__ ws, float* __restrict__ out) {
    __shared__ __align__(16) char lds[74752];
    char*  pq_s = lds;                      // [256][128B] XOR-swz psi; first 4KB = m_s
    char*  breg = lds + 32768;              // 40KB: xs dbuf (2x20480); w2_s alias
    float* bo_s = (float*)(lds + 73728);    // [256]

    const int b = blockIdx.y, px0 = blockIdx.x * 256;
    const int t = threadIdx.x, w = t >> 6, l = t & 63;
    const int h = w >> 1;                   // head
    const int pxw = (w & 1) * 128;          // px half owned in MFMA phases
    const int stag = blockIdx.x & 7;        // K-loop start stagger
    const float* __restrict__ sv = ws + OFF_S + b * C_;
    const float* __restrict__ tv = ws + OFF_T + b * C_;
    const unsigned short* __restrict__ wkvq16 = (const unsigned short*)(ws + OFF_WKVQ);
    const float* __restrict__ xb = x + (size_t)b * C_ * N_ + px0;

    if (t < 256) bo_s[t] = bo[t];
    float* m_s = (float*)pq_s;              // 4KB scratch, read only in W2 phase
    for (int i = t; i < 1024; i += 512) m_s[i] = ws[OFF_M + b * 1024 + i];
    float zr[4];
    #pragma unroll
    for (int r = 0; r < 4; ++r)
        zr[r] = ws[OFF_Z + b * 64 + h * 16 + (l >> 4) * 4 + r];

    // Wq fragments, slot kk holds channel-chunk (stag+kk)&7 (reg index static)
    short8b afq[8];
    {
        const unsigned short* wq = wkvq16
            + (size_t)(128 + h * 16 + (l & 15)) * 256 + (l >> 4) * 8;
        #pragma unroll
        for (int kk = 0; kk < 8; ++kk)
            afq[kk] = *(const short8b*)(wq + ((stag + kk) & 7) * 32);
    }

    const int px_ = t & 255, half = t >> 8;
    char* xs0 = breg;
    char* xs1 = breg + 20480;

    f32x4 accq[8];
    #pragma unroll
    for (int j = 0; j < 8; ++j) accq[j] = (f32x4){0.f, 0.f, 0.f, 0.f};

    // ---- phase 1: phi_q GEMM, double-buffered, staggered chunk order ----
    {   // prologue: stage chunk stag into xs0
        float xf[16];
        #pragma unroll
        for (int i = 0; i < 16; ++i)
            xf[i] = xb[(size_t)(stag * 32 + half * 16 + i) * N_ + px_];
        #pragma unroll
        for (int i = 0; i < 8; ++i) {
            const int c = stag * 32 + half * 16 + 2 * i;
            const float a0 = fmaf(xf[2 * i],     sv[c],     tv[c]);
            const float a1 = fmaf(xf[2 * i + 1], sv[c + 1], tv[c + 1]);
            *(unsigned int*)(xs0 + px_ * 80 + (half * 16 + 2 * i) * 2) =
                ((unsigned int)bf16u(a1) << 16) | bf16u(a0);
        }
    }
    __syncthreads();
    #pragma unroll
    for (int kk = 0; kk < 8; ++kk) {
        char* xcur = (kk & 1) ? xs1 : xs0;
        char* xnxt = (kk & 1) ? xs0 : xs1;
        const int ksn = (stag + kk + 1) & 7;
        float xg[16];
        if (kk < 7) {                        // issue next-chunk loads EARLY
            #pragma unroll
            for (int i = 0; i < 16; ++i)
                xg[i] = xb[(size_t)(ksn * 32 + half * 16 + i) * N_ + px_];
        }
        #pragma unroll
        for (int ct = 0; ct < 8; ++ct) {     // MFMA on current buffer
            const short8b bfr = *(const short8b*)(xcur + (pxw + ct * 16 + (l & 15)) * 80
                                                  + (l >> 4) * 16);
            accq[ct] = __builtin_amdgcn_mfma_f32_16x16x32_bf16(
                           afq[kk], bfr, accq[ct], 0, 0, 0);
        }
        if (kk < 7) {                        // fold + write next buffer LATE
            #pragma unroll
            for (int i = 0; i < 8; ++i) {
                const int c = ksn * 32 + half * 16 + 2 * i;
                const float a0 = fmaf(xg[2 * i],     sv[c],     tv[c]);
                const float a1 = fmaf(xg[2 * i + 1], sv[c + 1], tv[c + 1]);
                *(unsigned int*)(xnxt + px_ * 80 + (half * 16 + 2 * i) * 2) =
                    ((unsigned int)bf16u(a1) << 16) | bf16u(a0);
            }
        }
        __syncthreads();
    }

    // ---- W2 = Wo·M^T -> w2_s (aliases x staging; phase 1 fully drained) ----
    char* w2_s = breg;                       // [256][128B] XOR-swizzled
    {
        const int c = t & 255, hp = t >> 8;  // 2 heads per thread
        #pragma unroll
        for (int hh = 0; hh < 2; ++hh) {
            const int hw = hp * 2 + hh;
            float wrow[16];
            #pragma unroll
            for (int j = 0; j < 4; ++j)
                *(float4*)&wrow[j * 4] = *(const float4*)&Wo[c * 64 + hw * 16 + j * 4];
            float av[16];
            #pragma unroll
            for (int d = 0; d < 16; ++d) {
                float a = 0.f;
                #pragma unroll
                for (int e = 0; e < 16; ++e)
                    a = fmaf(wrow[e], m_s[hw * 256 + d * 16 + e], a);
                av[d] = a;
            }
            #pragma unroll
            for (int j = 0; j < 8; ++j) {
                const unsigned int pk = (unsigned int)bf16u(av[2 * j])
                                      | ((unsigned int)bf16u(av[2 * j + 1]) << 16);
                *(unsigned int*)(w2_s + c * 128 + ((hw * 32 + j * 4) ^ ((c & 7) << 4))) = pk;
            }
        }
    }
    __syncthreads();   // m_s reads done before psi overwrites pq_s

    // ---- phi, per-pixel den (in-wave shuffle), psi -> pq_s (swizzled) ----
    #pragma unroll
    for (int ct = 0; ct < 8; ++ct) {
        float p[4];
        #pragma unroll
        for (int r = 0; r < 4; ++r) {
            const float v = accq[ct][r];
            p[r] = v > 0.f ? v + 1.f : __expf(v);
        }
        float dp = 0.f;
        #pragma unroll
        for (int r = 0; r < 4; ++r) dp = fmaf(zr[r], p[r], dp);
        dp += __shfl_xor(dp, 16);
        dp += __shfl_xor(dp, 32);
        const float rd = 1.f / fmaxf(dp, 1e-4f);
        const int px = pxw + ct * 16 + (l & 15);
        const unsigned int lo = (unsigned int)bf16u(p[0] * rd)
                              | ((unsigned int)bf16u(p[1] * rd) << 16);
        const unsigned int hi = (unsigned int)bf16u(p[2] * rd)
                              | ((unsigned int)bf16u(p[3] * rd) << 16);
        const int off = (h * 32 + (l >> 4) * 8) ^ ((px & 7) << 4);
        *(unsigned long long*)(pq_s + px * 128 + off) =
            (unsigned long long)lo | ((unsigned long long)hi << 32);
    }
    __syncthreads();   // psi + W2 visible to all waves

    // ---- phase 3: out = W2 · psi (K=64); staggered rt order on writes ----
    const float gate = ws[OFF_GATE + b];
    const float* __restrict__ xr = x + (size_t)b * C_ * N_ + px0;
    float* __restrict__ ob = out + (size_t)b * C_ * N_ + px0;
    #pragma unroll
    for (int rti = 0; rti < 4; ++rti) {
        const int rt = (rti + blockIdx.x) & 3;
        f32x4 acc[8];
        #pragma unroll
        for (int j = 0; j < 8; ++j) acc[j] = (f32x4){0.f, 0.f, 0.f, 0.f};
        const int row = h * 64 + rt * 16 + (l & 15);
        #pragma unroll
        for (int ksi = 0; ksi < 2; ++ksi) {
            const short8b af = *(const short8b*)(w2_s + row * 128
                                 + ((ksi * 64 + (l >> 4) * 16) ^ ((row & 7) << 4)));
            #pragma unroll
            for (int ct = 0; ct < 8; ++ct) {
                const int px = pxw + ct * 16 + (l & 15);
                const short8b bfr = *(const short8b*)(pq_s + px * 128
                                 + ((ksi * 64 + (l >> 4) * 16) ^ ((px & 7) << 4)));
                acc[ct] = __builtin_amdgcn_mfma_f32_16x16x32_bf16(
                              af, bfr, acc[ct], 0, 0, 0);
            }
        }
        #pragma unroll
        for (int ct = 0; ct < 8; ++ct) {
            const int px = pxw + ct * 16 + (l & 15);
            #pragma unroll
            for (int r = 0; r < 4; ++r) {
                const int orow = h * 64 + rt * 16 + (l >> 4) * 4 + r;
                const size_t off = (size_t)orow * N_ + px;
                ob[off] = fmaf(gate, acc[ct][r] + bo_s[orow], xr[off]);
            }
        }
    }
}

// ---------------------------------------------------------------------------
extern "C" void kernel_launch(void* const* d_in, const int* in_sizes, int n_in,
                              void* d_out, int out_size, void* d_ws, size_t ws_size,
                              hipStream_t stream) {
    const float* x   = (const float*)d_in[0];
    const float* gnw = (const float*)d_in[1];
    const float* gnb = (const float*)d_in[2];
    const float* Wk  = (const float*)d_in[3];
    const float* Wv  = (const float*)d_in[4];
    const float* Wq  = (const float*)d_in[5];
    const float* Wo  = (const float*)d_in[6];
    const float* bo  = (const float*)d_in[7];
    const float* M0  = (const float*)d_in[8];
    const float* Z0  = (const float*)d_in[9];
    const float* g1w = (const float*)d_in[10];
    const float* g1b = (const float*)d_in[11];
    const float* g2w = (const float*)d_in[12];
    const float* g2b = (const float*)d_in[13];
    float* out = (float*)d_out;
    float* ws  = (float*)d_ws;

    hipLaunchKernelGGL(k_stats,  dim3(B_ * C_), dim3(256), 0, stream, x, ws);
    hipLaunchKernelGGL(k_cvtw,   dim3(192),     dim3(256), 0, stream, Wk, Wv, Wq, ws);
    hipLaunchKernelGGL(k_prep,   dim3(B_),      dim3(256), 0, stream,
                       gnw, gnb, M0, Z0, g1w, g1b, g2w, g2b, ws,
                       out + (size_t)B_ * C_ * N_);
    hipLaunchKernelGGL(k_projmz, dim3(N_ / 128, B_), dim3(256), 0, stream, x, ws);
    hipLaunchKernelGGL(k_out5,   dim3(N_ / 256, B_), dim3(512), 0, stream,
                       x, Wo, bo, ws, out);
}